// Round 13
// baseline (1276.428 us; speedup 1.0000x reference)
//
#include <hip/hip_runtime.h>
#include <cstddef>
#include <cstdint>

#define B_ 64
#define T_ 800
#define D_ 80
#define H_ 128
#define K_ 39
#define BT_ (B_ * T_)   // 51200

typedef _Float16 h2_t  __attribute__((ext_vector_type(2)));
typedef _Float16 f16x8 __attribute__((ext_vector_type(8)));
typedef float    f32x4 __attribute__((ext_vector_type(4)));

__device__ __forceinline__ float fdot2_(h2_t a, h2_t b, float c) {
#if __has_builtin(__builtin_amdgcn_fdot2)
  return __builtin_amdgcn_fdot2(a, b, c, false);
#else
  return c + (float)a.x * (float)b.x + (float)a.y * (float)b.y;
#endif
}

__device__ __forceinline__ h2_t asH2u_(uint32_t u) { return __builtin_bit_cast(h2_t, u); }

__device__ __forceinline__ float sigf_(float x)  { return 1.0f / (1.0f + __expf(-x)); }
__device__ __forceinline__ float tanhf_(float x) { return 2.0f / (1.0f + __expf(-2.0f * x)) - 1.0f; }

__device__ __forceinline__ float laneb_(float v, int lane) {
  return __builtin_bit_cast(float, __builtin_amdgcn_readlane(__builtin_bit_cast(int, v), lane));
}
__device__ __forceinline__ uint32_t lanebu_(uint32_t v, int lane) {
  return (uint32_t)__builtin_amdgcn_readlane((int)v, lane);
}

// VALU lane-pair swap via DPP quad_perm[1,0,3,2] (0xB1): lane 2k <-> 2k+1.
__device__ __forceinline__ float dppswap1_(float v) {
  return __builtin_bit_cast(float,
    __builtin_amdgcn_mov_dpp(__builtin_bit_cast(int, v), 0xB1, 0xF, 0xF, true));
}

// LDS-only barrier: waits LDS ops but does NOT drain vmem.
__device__ __forceinline__ void barrier_lds_() {
  asm volatile("s_waitcnt lgkmcnt(0)" ::: "memory");
  __builtin_amdgcn_s_barrier();
}

// lstm lane->gate-rows mapping within a 256-thread group: wave w = t8>>6,
// lane L: unit = w*32 + (L>>1), role = L&1. role0 owns (i,g), role1 (f,o).
__device__ __forceinline__ void rows_of_(int t8, int& unit, int& role, int& r0, int& r1) {
  const int w = t8 >> 6, L = t8 & 63;
  unit = w * 32 + (L >> 1);
  role = L & 1;
  r0 = role * H_ + unit;            // i (role0) or f (role1)
  r1 = 2 * H_ + role * H_ + unit;   // g (role0) or o (role1)
}

// ---------------------------------------------------------------------------
// xw via MFMA 16x16x32 f16, PAIRED output layout (unchanged).
// ---------------------------------------------------------------------------
__global__ __launch_bounds__(256, 1)
void xw_kernel(const float* __restrict__ x,
               const float* __restrict__ Wih_f, const float* __restrict__ Wih_b,
               _Float16* __restrict__ xw)
{
  const int dir = blockIdx.x & 1;
  const int mc  = blockIdx.x >> 1;           // 0..99
  const float* W = dir ? Wih_b : Wih_f;

  const int tid  = threadIdx.x;
  const int w    = tid >> 6;
  const int lane = tid & 63;
  const int lm   = lane & 15;
  const int quad = lane >> 4;
  const int selw = w >> 1;                   // 0: i/f (.x slot), 1: g/o (.y slot)
  const int rolw = w & 1;

  f16x8 Bf[8][3];
  #pragma unroll
  for (int nt = 0; nt < 8; ++nt) {
    const int r = w * 128 + nt * 16 + lm;
    #pragma unroll
    for (int kt = 0; kt < 3; ++kt) {
      const int kb = kt * 32 + quad * 8;
      #pragma unroll
      for (int j = 0; j < 8; ++j) {
        const int k = kb + j;
        Bf[nt][kt][j] = (k < D_) ? (_Float16)W[(size_t)r * D_ + k] : (_Float16)0.0f;
      }
    }
  }

  __shared__ alignas(16) _Float16 xs[128 * 96];   // 24 KB, K padded to 96
  for (int i = tid; i < 128 * 96; i += 256) xs[i] = (_Float16)0.0f;

  for (int cc = 0; cc < 4; ++cc) {
    const int base = mc * 512 + cc * 128;
    __syncthreads();
    {
      const float4* src = (const float4*)(x + (size_t)base * D_);
      for (int i = tid; i < 128 * D_ / 4; i += 256) {
        float4 v = src[i];
        const int row = i / 20, col = (i % 20) * 4;
        h2_t p0, p1;
        p0.x = (_Float16)v.x; p0.y = (_Float16)v.y;
        p1.x = (_Float16)v.z; p1.y = (_Float16)v.w;
        uint2 pk;
        pk.x = __builtin_bit_cast(uint32_t, p0);
        pk.y = __builtin_bit_cast(uint32_t, p1);
        *(uint2*)&xs[row * 96 + col] = pk;
      }
    }
    __syncthreads();

    #pragma unroll
    for (int mt = 0; mt < 8; ++mt) {
      f16x8 Af[3];
      #pragma unroll
      for (int kt = 0; kt < 3; ++kt)
        Af[kt] = *(const f16x8*)&xs[(mt * 16 + lm) * 96 + kt * 32 + quad * 8];

      f32x4 acc[8];
      #pragma unroll
      for (int nt = 0; nt < 8; ++nt) acc[nt] = (f32x4){0.f, 0.f, 0.f, 0.f};
      #pragma unroll
      for (int kt = 0; kt < 3; ++kt)
        #pragma unroll
        for (int nt = 0; nt < 8; ++nt)
          acc[nt] = __builtin_amdgcn_mfma_f32_16x16x32_f16(Af[kt], Bf[nt][kt], acc[nt], 0, 0, 0);

      #pragma unroll
      for (int nt = 0; nt < 8; ++nt) {
        const int unit = nt * 16 + lm;
        const int ptid = (unit >> 5) * 64 + (unit & 31) * 2 + rolw;
        #pragma unroll
        for (int rg = 0; rg < 4; ++rg) {
          const int bt = base + mt * 16 + quad * 4 + rg;
          xw[((size_t)dir * BT_ + bt) * 512 + ptid * 2 + selw] = (_Float16)acc[nt][rg];
        }
      }
    }
  }
}

// ---------------------------------------------------------------------------
// Recurrent LSTM, fwd+bwd MERGED per block. Grid 64, 512 threads:
// group g = tid>>8 handles direction g of batch blockIdx.x. The two groups
// are independent (separate LDS buffers) except the shared barrier -> their
// waves interleave on the 4 SIMDs (2 waves/SIMD), hiding each other's
// readlane-hazard and LDS/transcendental latency stalls (the ~1100 cyc/step
// that VALUBusy=34% showed exposed at 1 wave/SIMD).
// ---------------------------------------------------------------------------
template<int USE_XW>
__global__ __launch_bounds__(512, 2)
void lstm_kernel(const float* __restrict__ x,
                 const float* __restrict__ Wih_f, const float* __restrict__ Whh_f,
                 const float* __restrict__ bih_f, const float* __restrict__ bhh_f,
                 const float* __restrict__ Wih_b, const float* __restrict__ Whh_b,
                 const float* __restrict__ bih_b, const float* __restrict__ bhh_b,
                 const _Float16* __restrict__ xw,
                 _Float16* __restrict__ hcat)
{
  const int bb  = blockIdx.x;          // batch
  const int tid = threadIdx.x;
  const int g   = tid >> 8;            // 0 = fwd, 1 = bwd
  const int t8  = tid & 255;
  const int dir = g;
  const float* Whh = dir ? Whh_b : Whh_f;
  const float* Wih = dir ? Wih_b : Wih_f;
  const float* bih = dir ? bih_b : bih_f;
  const float* bhh = dir ? bhh_b : bhh_f;

  const int lane = tid & 63;
  int unit, role, r0, r1; rows_of_(t8, unit, role, r0, r1);

  h2_t w0[64], w1[64];
  #pragma unroll
  for (int j = 0; j < 64; ++j) {
    float2 a = *(const float2*)(Whh + (size_t)r0 * H_ + 2 * j);
    float2 d = *(const float2*)(Whh + (size_t)r1 * H_ + 2 * j);
    w0[j].x = (_Float16)a.x; w0[j].y = (_Float16)a.y;
    w1[j].x = (_Float16)d.x; w1[j].y = (_Float16)d.y;
  }
  h2_t wx0[40], wx1[40];
  if (!USE_XW) {
    #pragma unroll
    for (int i = 0; i < 40; ++i) {
      float2 a = *(const float2*)(Wih + (size_t)r0 * D_ + 2 * i);
      float2 d = *(const float2*)(Wih + (size_t)r1 * D_ + 2 * i);
      wx0[i].x = (_Float16)a.x; wx0[i].y = (_Float16)a.y;
      wx1[i].x = (_Float16)d.x; wx1[i].y = (_Float16)d.y;
    }
  }
  const float bias0 = bih[r0] + bhh[r0];
  const float bias1 = bih[r1] + bhh[r1];

  __shared__ alignas(8) _Float16 hsf[2][2][H_];   // [group][parity][unit]
  __shared__ uint32_t xs2[2][2][64];              // fallback x staging

  if (t8 < H_) hsf[g][0][t8] = (_Float16)0.0f;
  if (!USE_XW && t8 < 64) { xs2[g][0][t8] = 0u; xs2[g][1][t8] = 0u; }
  float c = 0.0f;   // role1 owns cell state of its unit

  const uint32_t* xwdu = (const uint32_t*)xw + ((size_t)dir * BT_ + (size_t)bb * T_) * 256;
  const float*    xb   = x + (size_t)bb * T_ * D_;
  _Float16*       hb   = hcat + (size_t)bb * T_ * (2 * H_) + dir * H_;

  uint32_t xwA = 0u, xwB = 0u;
  h2_t xpend; xpend.x = (_Float16)0.f; xpend.y = (_Float16)0.f;
  {
    const int tq0 = dir ? (T_ - 1) : 0;
    const int tq1 = dir ? (T_ - 2) : 1;
    if (USE_XW) {
      xwA = xwdu[(size_t)tq0 * 256 + t8];
      xwB = xwdu[(size_t)tq1 * 256 + t8];
    } else if (t8 < 40) {
      float2 v0 = *(const float2*)(xb + (size_t)tq0 * D_ + 2 * t8);
      h2_t p; p.x = (_Float16)v0.x; p.y = (_Float16)v0.y;
      xs2[g][0][t8] = __builtin_bit_cast(uint32_t, p);
      float2 v1 = *(const float2*)(xb + (size_t)tq1 * D_ + 2 * t8);
      xpend.x = (_Float16)v1.x; xpend.y = (_Float16)v1.y;
    }
  }
  __syncthreads();

  auto step = [&](int tt, int par, uint32_t& xwreg) {
    const int t = dir ? (T_ - 1 - tt) : tt;
    float a0, a1, b0, b1;
    if (USE_XW) {
      const h2_t xv = asH2u_(xwreg);
      a0 = bias0 + (float)xv.x;
      b0 = bias1 + (float)xv.y;
      a1 = 0.f; b1 = 0.f;
      const int ttc = (tt + 2 < T_) ? (tt + 2) : (T_ - 1);
      const int tq2 = dir ? (T_ - 1 - ttc) : ttc;
      xwreg = xwdu[(size_t)tq2 * 256 + t8];    // prefetch; consumed 2 steps later
    } else {
      a0 = bias0; a1 = 0.f; b0 = bias1; b1 = 0.f;
      if (t8 < 40) {
        xs2[g][par ^ 1][t8] = __builtin_bit_cast(uint32_t, xpend);
        const int ttc = (tt + 2 < T_) ? (tt + 2) : (T_ - 1);
        const int tq2 = dir ? (T_ - 1 - ttc) : ttc;
        float2 v = *(const float2*)(xb + (size_t)tq2 * D_ + 2 * t8);
        xpend.x = (_Float16)v.x; xpend.y = (_Float16)v.y;
      }
      uint32_t xreg = xs2[g][par][lane];
      #pragma unroll
      for (int j = 0; j < 40; j += 2) {
        h2_t q0 = asH2u_(lanebu_(xreg, j));
        h2_t q1 = asH2u_(lanebu_(xreg, j + 1));
        a0 = fdot2_(wx0[j],     q0, a0); b0 = fdot2_(wx1[j],     q0, b0);
        a1 = fdot2_(wx0[j + 1], q1, a1); b1 = fdot2_(wx1[j + 1], q1, b1);
      }
    }

    const uint32_t h2reg = ((const uint32_t*)hsf[g][par])[lane];
    #pragma unroll
    for (int j = 0; j < 64; j += 2) {
      h2_t hv0 = asH2u_(lanebu_(h2reg, j));
      h2_t hv1 = asH2u_(lanebu_(h2reg, j + 1));
      a0 = fdot2_(w0[j],     hv0, a0); b0 = fdot2_(w1[j],     hv0, b0);
      a1 = fdot2_(w0[j + 1], hv1, a1); b1 = fdot2_(w1[j + 1], hv1, b1);
    }
    const float ga = a0 + a1;   // i (role0) or f (role1)
    const float gb = b0 + b1;   // g (role0) or o (role1)

    float p = 0.f, sf = 0.f, so = 0.f;
    if (role == 0) p = sigf_(ga) * tanhf_(gb);
    else { sf = sigf_(ga); so = sigf_(gb); }
    const float ex = dppswap1_(p);              // VALU swap, lane 2k <-> 2k+1
    if (role) {
      c = sf * c + ex;
      const float h = so * tanhf_(c);
      hsf[g][par ^ 1][unit] = (_Float16)h;
      hb[(size_t)t * (2 * H_) + unit] = (_Float16)h;  // async, never drained
    }
    barrier_lds_();
  };

  for (int tb = 0; tb < T_; tb += 2) {
    step(tb,     0, xwA);
    step(tb + 1, 1, xwB);
  }
}

// ---------------------------------------------------------------------------
// Emissions via MFMA (unchanged).
// ---------------------------------------------------------------------------
__global__ __launch_bounds__(256, 1)
void emis_kernel(const _Float16* __restrict__ hcat,
                 const float* __restrict__ Wp, const float* __restrict__ bp,
                 float* __restrict__ em)
{
  const int tid  = threadIdx.x;
  const int w    = tid >> 6;
  const int lane = tid & 63;
  const int lm   = lane & 15;
  const int quad = lane >> 4;

  f16x8 Bf[3][8];
  float bias[3];
  #pragma unroll
  for (int nt = 0; nt < 3; ++nt) {
    const int n = nt * 16 + lm;
    const bool valid = n < K_;
    bias[nt] = valid ? bp[n] : 0.0f;
    #pragma unroll
    for (int kt = 0; kt < 8; ++kt) {
      const int kb = kt * 32 + quad * 8;
      #pragma unroll
      for (int j = 0; j < 8; ++j)
        Bf[nt][kt][j] = valid ? (_Float16)Wp[(size_t)n * 256 + kb + j] : (_Float16)0.0f;
    }
  }

  #pragma unroll
  for (int q = 0; q < 4; ++q) {
    const int mt  = blockIdx.x * 16 + w * 4 + q;
    const int bt0 = mt * 16;

    f16x8 Af[8];
    const _Float16* ab = hcat + ((size_t)bt0 + lm) * 256;
    #pragma unroll
    for (int kt = 0; kt < 8; ++kt)
      Af[kt] = *(const f16x8*)(ab + kt * 32 + quad * 8);

    f32x4 acc[3];
    #pragma unroll
    for (int nt = 0; nt < 3; ++nt) acc[nt] = (f32x4){0.f, 0.f, 0.f, 0.f};
    #pragma unroll
    for (int kt = 0; kt < 8; ++kt)
      #pragma unroll
      for (int nt = 0; nt < 3; ++nt)
        acc[nt] = __builtin_amdgcn_mfma_f32_16x16x32_f16(Af[kt], Bf[nt][kt], acc[nt], 0, 0, 0);

    #pragma unroll
    for (int nt = 0; nt < 3; ++nt) {
      const int n = nt * 16 + lm;
      if (n < K_) {
        #pragma unroll
        for (int rg = 0; rg < 4; ++rg) {
          const int row = bt0 + quad * 4 + rg;
          em[(size_t)row * K_ + n] = acc[nt][rg] + bias[nt];
        }
      }
    }
  }
}

// ---------------------------------------------------------------------------
// Fused CRF den+num. Grid 64, 256 threads. em staged in LDS (2 phases).
// Den (wave 0): the v-broadcast now goes through LDS (pbuf write + 10
// ds_read_b128) instead of 39 v_readlane — readlane's VALU->SGPR->VALU
// hazard stalls (~500 cyc/step, the R12 residual) become pure-VGPR FMAs.
// Early exit at len (R12 ran 816 fixed steps). Waves 1-3: numerator.
// ---------------------------------------------------------------------------
__global__ __launch_bounds__(256)
void crf_dn_kernel(const float* __restrict__ em,
                   const int* __restrict__ labels, const int* __restrict__ lengths,
                   const float* __restrict__ start_t, const float* __restrict__ end_t,
                   const float* __restrict__ trans,
                   float* __restrict__ dn)
{
  const int b    = blockIdx.x;
  const int tid  = threadIdx.x;
  const int wv   = tid >> 6;
  const int lane = tid & 63;
  const int len  = lengths[b];
  const float* emb = em + (size_t)b * T_ * K_;

  __shared__ alignas(16) float ems[408 * K_];   // 63.6 KB
  __shared__ alignas(16) float pbuf[64];
  __shared__ float s_red[4];

  float et[K_];
  float v = 0.f, off_acc = 0.f, num_acc = 0.f;

  if (wv == 0) {
    #pragma unroll
    for (int j = 0; j < K_; ++j)
      et[j] = (lane < K_) ? __expf(trans[j * K_ + lane]) : 0.0f;
    float a0 = (lane < K_) ? (start_t[lane] + emb[lane]) : -1e30f;
    float m = a0;
    #pragma unroll
    for (int off = 32; off > 0; off >>= 1) m = fmaxf(m, __shfl_xor(m, off));
    v = __expf(a0 - m);               // lanes >= 39 -> 0
    off_acc = m;
  }

  for (int p = 0; p < 2; ++p) {
    const int rbase = p * 408;                   // staged row range start
    const int rcnt  = p ? 392 : 408;
    {
      const float4* src = (const float4*)(emb + (size_t)rbase * K_);
      for (int i = tid; i < rcnt * K_ / 4; i += 256)
        ((float4*)ems)[i] = src[i];
    }
    __syncthreads();

    if (wv == 0) {
      const int ts = p ? 408 : 1;
      const int te = (p ? T_ : 408) < len ? (p ? T_ : 408) : len;
      if (ts < te) {
        float emn = (lane < K_) ? ems[(ts - rbase) * K_ + lane] : 0.f;
        for (int t = ts; t < te; ++t) {
          const float emc = emn;
          const int tn = (t + 1 < te) ? (t + 1) : (te - 1);
          emn = (lane < K_) ? ems[(tn - rbase) * K_ + lane] : 0.f;   // prefetch

          pbuf[lane] = v;                         // publish (same-wave ordered)
          const float4* pb4 = (const float4*)pbuf;
          float vv[40];
          #pragma unroll
          for (int i = 0; i < 10; ++i) {
            float4 q = pb4[i];                    // broadcast, conflict-free
            vv[4 * i] = q.x; vv[4 * i + 1] = q.y;
            vv[4 * i + 2] = q.z; vv[4 * i + 3] = q.w;
          }
          float s0 = 0.f, s1 = 0.f, s2 = 0.f, s3 = 0.f;
          #pragma unroll
          for (int j = 0; j < 36; j += 4) {
            s0 = fmaf(vv[j],     et[j],     s0);
            s1 = fmaf(vv[j + 1], et[j + 1], s1);
            s2 = fmaf(vv[j + 2], et[j + 2], s2);
            s3 = fmaf(vv[j + 3], et[j + 3], s3);
          }
          s0 = fmaf(vv[36], et[36], s0);
          s1 = fmaf(vv[37], et[37], s1);
          s2 = fmaf(vv[38], et[38], s2);
          v = ((s0 + s1) + (s2 + s3)) * __expf(emc);
          if ((t & 3) == 0) {                     // algebra-neutral renorm
            const float sc = laneb_(v, 0);        // strictly positive
            v *= __builtin_amdgcn_rcpf(sc);
            off_acc += __logf(sc);
          }
        }
      }
    } else if (p == 0) {
      // numerator over full range (global reads, latency-tolerant)
      const int idx = tid - 64;       // 0..191
      for (int t = 1 + idx; t < len; t += 192) {
        const int lp = labels[b * T_ + t - 1];
        const int lc = labels[b * T_ + t];
        num_acc += trans[lp * K_ + lc] + emb[(size_t)t * K_ + lc];
      }
      if (tid == 64) {                // edge terms on one lane
        const int l0 = labels[b * T_];
        const int ll = labels[b * T_ + len - 1];
        num_acc += start_t[l0] + emb[l0] + end_t[ll];
      }
    }
    __syncthreads();
  }

  if (wv == 0) {
    float w = (lane < K_) ? v * __expf(end_t[lane]) : 0.0f;
    #pragma unroll
    for (int off = 32; off > 0; off >>= 1) w += __shfl_xor(w, off);
    if (lane == 0) s_red[0] = off_acc + __logf(w);
  } else {
    float acc = num_acc;
    #pragma unroll
    for (int off = 32; off > 0; off >>= 1) acc += __shfl_xor(acc, off);
    if (lane == 0) s_red[wv] = acc;
  }
  __syncthreads();
  if (tid == 0) dn[b] = s_red[0] - (s_red[1] + s_red[2] + s_red[3]);
}

// out = mean(dn) over the 64 batch elements (one wave).
__global__ void finalize_kernel(const float* __restrict__ dn, float* __restrict__ out)
{
  const int tid = threadIdx.x;   // 64
  float v = dn[tid];
  #pragma unroll
  for (int off = 32; off > 0; off >>= 1) v += __shfl_down(v, off);
  if (tid == 0) out[0] = v * (1.0f / 64.0f);
}

extern "C" void kernel_launch(void* const* d_in, const int* in_sizes, int n_in,
                              void* d_out, int out_size, void* d_ws, size_t ws_size,
                              hipStream_t stream)
{
  (void)in_sizes; (void)n_in; (void)out_size;
  const float* features = (const float*)d_in[0];
  const int*   lengths  = (const int*)d_in[1];
  const int*   labels   = (const int*)d_in[2];
  const float* Wih_f = (const float*)d_in[3];
  const float* Whh_f = (const float*)d_in[4];
  const float* bih_f = (const float*)d_in[5];
  const float* bhh_f = (const float*)d_in[6];
  const float* Wih_b = (const float*)d_in[7];
  const float* Whh_b = (const float*)d_in[8];
  const float* bih_b = (const float*)d_in[9];
  const float* bhh_b = (const float*)d_in[10];
  const float* Wp      = (const float*)d_in[11];
  const float* bp      = (const float*)d_in[12];
  const float* start_t = (const float*)d_in[13];
  const float* end_t   = (const float*)d_in[14];
  const float* trans   = (const float*)d_in[15];
  float* out = (float*)d_out;

  // ws layout (bytes): hcat f16 [0, 26214400) ; em f32 [26214400, +7987200) ;
  // dn 256 B ; xw f16 [34202112, +104857600) if ws is big enough.
  char* wsc = (char*)d_ws;
  _Float16* hcatH = (_Float16*)wsc;
  float*    em    = (float*)(wsc + 26214400);
  float*    dn    = (float*)(wsc + 26214400 + 7987200);
  _Float16* xwH   = (_Float16*)(wsc + 34202112);
  const bool big  = ws_size >= (size_t)34202112 + 104857600;

  if (big) {
    hipLaunchKernelGGL(xw_kernel, dim3(200), dim3(256), 0, stream,
                       features, Wih_f, Wih_b, xwH);
    hipLaunchKernelGGL((lstm_kernel<1>), dim3(B_), dim3(512), 0, stream,
                       features, Wih_f, Whh_f, bih_f, bhh_f,
                       Wih_b, Whh_b, bih_b, bhh_b, xwH, hcatH);
  } else {
    hipLaunchKernelGGL((lstm_kernel<0>), dim3(B_), dim3(512), 0, stream,
                       features, Wih_f, Whh_f, bih_f, bhh_f,
                       Wih_b, Whh_b, bih_b, bhh_b, xwH, hcatH);
  }
  hipLaunchKernelGGL(emis_kernel, dim3(BT_ / 256), dim3(256), 0, stream,
                     hcatH, Wp, bp, em);
  hipLaunchKernelGGL(crf_dn_kernel, dim3(B_), dim3(256), 0, stream,
                     em, labels, lengths, start_t, end_t, trans, dn);
  hipLaunchKernelGGL(finalize_kernel, dim3(1), dim3(64), 0, stream,
                     dn, out);
}

// Round 14
// 870.996 us; speedup vs baseline: 1.4655x; 1.4655x over previous
//
#include <hip/hip_runtime.h>
#include <cstddef>
#include <cstdint>

#define B_ 64
#define T_ 800
#define D_ 80
#define H_ 128
#define K_ 39
#define BT_ (B_ * T_)   // 51200

typedef _Float16 h2_t  __attribute__((ext_vector_type(2)));
typedef _Float16 f16x8 __attribute__((ext_vector_type(8)));
typedef float    f32x4 __attribute__((ext_vector_type(4)));

__device__ __forceinline__ float fdot2_(h2_t a, h2_t b, float c) {
#if __has_builtin(__builtin_amdgcn_fdot2)
  return __builtin_amdgcn_fdot2(a, b, c, false);
#else
  return c + (float)a.x * (float)b.x + (float)a.y * (float)b.y;
#endif
}

__device__ __forceinline__ h2_t asH2u_(uint32_t u) { return __builtin_bit_cast(h2_t, u); }

__device__ __forceinline__ float sigf_(float x)  { return 1.0f / (1.0f + __expf(-x)); }
__device__ __forceinline__ float tanhf_(float x) { return 2.0f / (1.0f + __expf(-2.0f * x)) - 1.0f; }

__device__ __forceinline__ float laneb_(float v, int lane) {
  return __builtin_bit_cast(float, __builtin_amdgcn_readlane(__builtin_bit_cast(int, v), lane));
}
__device__ __forceinline__ uint32_t lanebu_(uint32_t v, int lane) {
  return (uint32_t)__builtin_amdgcn_readlane((int)v, lane);
}

// VALU lane-pair swap via DPP quad_perm[1,0,3,2] (0xB1): lane 2k <-> 2k+1.
__device__ __forceinline__ float dppswap1_(float v) {
  return __builtin_bit_cast(float,
    __builtin_amdgcn_mov_dpp(__builtin_bit_cast(int, v), 0xB1, 0xF, 0xF, true));
}

// LDS-only barrier: waits LDS ops but does NOT drain vmem.
__device__ __forceinline__ void barrier_lds_() {
  asm volatile("s_waitcnt lgkmcnt(0)" ::: "memory");
  __builtin_amdgcn_s_barrier();
}

// lstm lane->gate-rows mapping: wave w = tid>>6, lane L: unit = w*32+(L>>1),
// role = L&1. role0 owns (i,g) rows, role1 (f,o). DPP(1) pairs them.
__device__ __forceinline__ void rows_of_(int tid, int& unit, int& role, int& r0, int& r1) {
  const int w = tid >> 6, L = tid & 63;
  unit = w * 32 + (L >> 1);
  role = L & 1;
  r0 = role * H_ + unit;            // i (role0) or f (role1)
  r1 = 2 * H_ + role * H_ + unit;   // g (role0) or o (role1)
}

// ---------------------------------------------------------------------------
// xw via MFMA 16x16x32 f16, PAIRED output layout (unchanged).
// ---------------------------------------------------------------------------
__global__ __launch_bounds__(256, 1)
void xw_kernel(const float* __restrict__ x,
               const float* __restrict__ Wih_f, const float* __restrict__ Wih_b,
               _Float16* __restrict__ xw)
{
  const int dir = blockIdx.x & 1;
  const int mc  = blockIdx.x >> 1;           // 0..99
  const float* W = dir ? Wih_b : Wih_f;

  const int tid  = threadIdx.x;
  const int w    = tid >> 6;
  const int lane = tid & 63;
  const int lm   = lane & 15;
  const int quad = lane >> 4;
  const int selw = w >> 1;                   // 0: i/f (.x slot), 1: g/o (.y slot)
  const int rolw = w & 1;

  f16x8 Bf[8][3];
  #pragma unroll
  for (int nt = 0; nt < 8; ++nt) {
    const int r = w * 128 + nt * 16 + lm;
    #pragma unroll
    for (int kt = 0; kt < 3; ++kt) {
      const int kb = kt * 32 + quad * 8;
      #pragma unroll
      for (int j = 0; j < 8; ++j) {
        const int k = kb + j;
        Bf[nt][kt][j] = (k < D_) ? (_Float16)W[(size_t)r * D_ + k] : (_Float16)0.0f;
      }
    }
  }

  __shared__ alignas(16) _Float16 xs[128 * 96];   // 24 KB, K padded to 96
  for (int i = tid; i < 128 * 96; i += 256) xs[i] = (_Float16)0.0f;

  for (int cc = 0; cc < 4; ++cc) {
    const int base = mc * 512 + cc * 128;
    __syncthreads();
    {
      const float4* src = (const float4*)(x + (size_t)base * D_);
      for (int i = tid; i < 128 * D_ / 4; i += 256) {
        float4 v = src[i];
        const int row = i / 20, col = (i % 20) * 4;
        h2_t p0, p1;
        p0.x = (_Float16)v.x; p0.y = (_Float16)v.y;
        p1.x = (_Float16)v.z; p1.y = (_Float16)v.w;
        uint2 pk;
        pk.x = __builtin_bit_cast(uint32_t, p0);
        pk.y = __builtin_bit_cast(uint32_t, p1);
        *(uint2*)&xs[row * 96 + col] = pk;
      }
    }
    __syncthreads();

    #pragma unroll
    for (int mt = 0; mt < 8; ++mt) {
      f16x8 Af[3];
      #pragma unroll
      for (int kt = 0; kt < 3; ++kt)
        Af[kt] = *(const f16x8*)&xs[(mt * 16 + lm) * 96 + kt * 32 + quad * 8];

      f32x4 acc[8];
      #pragma unroll
      for (int nt = 0; nt < 8; ++nt) acc[nt] = (f32x4){0.f, 0.f, 0.f, 0.f};
      #pragma unroll
      for (int kt = 0; kt < 3; ++kt)
        #pragma unroll
        for (int nt = 0; nt < 8; ++nt)
          acc[nt] = __builtin_amdgcn_mfma_f32_16x16x32_f16(Af[kt], Bf[nt][kt], acc[nt], 0, 0, 0);

      #pragma unroll
      for (int nt = 0; nt < 8; ++nt) {
        const int unit = nt * 16 + lm;
        const int ptid = (unit >> 5) * 64 + (unit & 31) * 2 + rolw;
        #pragma unroll
        for (int rg = 0; rg < 4; ++rg) {
          const int bt = base + mt * 16 + quad * 4 + rg;
          xw[((size_t)dir * BT_ + bt) * 512 + ptid * 2 + selw] = (_Float16)acc[nt][rg];
        }
      }
    }
  }
}

// ---------------------------------------------------------------------------
// Recurrent LSTM — EXACT R12 revert: grid 128 (one WG per (b,dir), 1 WG/CU),
// 256 threads. R13's fwd/bwd merge (grid 64) halved CU count and regressed
// 545->933 (same failure as R4). Do not merge directions again.
// ---------------------------------------------------------------------------
template<int USE_XW>
__global__ __launch_bounds__(256, 1)
void lstm_kernel(const float* __restrict__ x,
                 const float* __restrict__ Wih_f, const float* __restrict__ Whh_f,
                 const float* __restrict__ bih_f, const float* __restrict__ bhh_f,
                 const float* __restrict__ Wih_b, const float* __restrict__ Whh_b,
                 const float* __restrict__ bih_b, const float* __restrict__ bhh_b,
                 const _Float16* __restrict__ xw,
                 _Float16* __restrict__ hcat)
{
  const int bb  = blockIdx.x & 63;
  const int dir = blockIdx.x >> 6;
  const float* Whh = dir ? Whh_b : Whh_f;
  const float* Wih = dir ? Wih_b : Wih_f;
  const float* bih = dir ? bih_b : bih_f;
  const float* bhh = dir ? bhh_b : bhh_f;

  const int tid  = threadIdx.x;
  const int lane = tid & 63;
  int unit, role, r0, r1; rows_of_(tid, unit, role, r0, r1);

  h2_t w0[64], w1[64];
  #pragma unroll
  for (int j = 0; j < 64; ++j) {
    float2 a = *(const float2*)(Whh + (size_t)r0 * H_ + 2 * j);
    float2 d = *(const float2*)(Whh + (size_t)r1 * H_ + 2 * j);
    w0[j].x = (_Float16)a.x; w0[j].y = (_Float16)a.y;
    w1[j].x = (_Float16)d.x; w1[j].y = (_Float16)d.y;
  }
  h2_t wx0[40], wx1[40];
  if (!USE_XW) {
    #pragma unroll
    for (int i = 0; i < 40; ++i) {
      float2 a = *(const float2*)(Wih + (size_t)r0 * D_ + 2 * i);
      float2 d = *(const float2*)(Wih + (size_t)r1 * D_ + 2 * i);
      wx0[i].x = (_Float16)a.x; wx0[i].y = (_Float16)a.y;
      wx1[i].x = (_Float16)d.x; wx1[i].y = (_Float16)d.y;
    }
  }
  const float bias0 = bih[r0] + bhh[r0];
  const float bias1 = bih[r1] + bhh[r1];

  __shared__ alignas(8) _Float16 hsf[2][H_];   // double-buffered h
  __shared__ uint32_t xs2[2][64];              // fallback x staging

  if (tid < H_) hsf[0][tid] = (_Float16)0.0f;
  if (!USE_XW && tid < 64) { xs2[0][tid] = 0u; xs2[1][tid] = 0u; }
  float c = 0.0f;   // role1 owns cell state of its unit

  const uint32_t* xwdu = (const uint32_t*)xw + ((size_t)dir * BT_ + (size_t)bb * T_) * 256;
  const float*    xb   = x + (size_t)bb * T_ * D_;
  _Float16*       hb   = hcat + (size_t)bb * T_ * (2 * H_) + dir * H_;

  uint32_t xwA = 0u, xwB = 0u;
  h2_t xpend; xpend.x = (_Float16)0.f; xpend.y = (_Float16)0.f;
  {
    const int tq0 = dir ? (T_ - 1) : 0;
    const int tq1 = dir ? (T_ - 2) : 1;
    if (USE_XW) {
      xwA = xwdu[(size_t)tq0 * 256 + tid];
      xwB = xwdu[(size_t)tq1 * 256 + tid];
    } else if (tid < 40) {
      float2 v0 = *(const float2*)(xb + (size_t)tq0 * D_ + 2 * tid);
      h2_t p; p.x = (_Float16)v0.x; p.y = (_Float16)v0.y;
      xs2[0][tid] = __builtin_bit_cast(uint32_t, p);
      float2 v1 = *(const float2*)(xb + (size_t)tq1 * D_ + 2 * tid);
      xpend.x = (_Float16)v1.x; xpend.y = (_Float16)v1.y;
    }
  }
  __syncthreads();

  auto step = [&](int tt, int par, uint32_t& xwreg) {
    const int t = dir ? (T_ - 1 - tt) : tt;
    float a0, a1, b0, b1;
    if (USE_XW) {
      const h2_t xv = asH2u_(xwreg);
      a0 = bias0 + (float)xv.x;
      b0 = bias1 + (float)xv.y;
      a1 = 0.f; b1 = 0.f;
      const int ttc = (tt + 2 < T_) ? (tt + 2) : (T_ - 1);
      const int tq2 = dir ? (T_ - 1 - ttc) : ttc;
      xwreg = xwdu[(size_t)tq2 * 256 + tid];   // prefetch; consumed 2 steps later
    } else {
      a0 = bias0; a1 = 0.f; b0 = bias1; b1 = 0.f;
      if (tid < 40) {
        xs2[par ^ 1][tid] = __builtin_bit_cast(uint32_t, xpend);
        const int ttc = (tt + 2 < T_) ? (tt + 2) : (T_ - 1);
        const int tq2 = dir ? (T_ - 1 - ttc) : ttc;
        float2 v = *(const float2*)(xb + (size_t)tq2 * D_ + 2 * tid);
        xpend.x = (_Float16)v.x; xpend.y = (_Float16)v.y;
      }
      uint32_t xreg = xs2[par][lane];
      #pragma unroll
      for (int j = 0; j < 40; j += 2) {
        h2_t q0 = asH2u_(lanebu_(xreg, j));
        h2_t q1 = asH2u_(lanebu_(xreg, j + 1));
        a0 = fdot2_(wx0[j],     q0, a0); b0 = fdot2_(wx1[j],     q0, b0);
        a1 = fdot2_(wx0[j + 1], q1, a1); b1 = fdot2_(wx1[j + 1], q1, b1);
      }
    }

    const uint32_t h2reg = ((const uint32_t*)hsf[par])[lane];
    #pragma unroll
    for (int j = 0; j < 64; j += 2) {
      h2_t hv0 = asH2u_(lanebu_(h2reg, j));
      h2_t hv1 = asH2u_(lanebu_(h2reg, j + 1));
      a0 = fdot2_(w0[j],     hv0, a0); b0 = fdot2_(w1[j],     hv0, b0);
      a1 = fdot2_(w0[j + 1], hv1, a1); b1 = fdot2_(w1[j + 1], hv1, b1);
    }
    const float ga = a0 + a1;   // i (role0) or f (role1)
    const float gb = b0 + b1;   // g (role0) or o (role1)

    float p = 0.f, sf = 0.f, so = 0.f;
    if (role == 0) p = sigf_(ga) * tanhf_(gb);
    else { sf = sigf_(ga); so = sigf_(gb); }
    const float ex = dppswap1_(p);              // VALU swap, lane 2k <-> 2k+1
    if (role) {
      c = sf * c + ex;
      const float h = so * tanhf_(c);
      hsf[par ^ 1][unit] = (_Float16)h;
      hb[(size_t)t * (2 * H_) + unit] = (_Float16)h;  // async, never drained
    }
    barrier_lds_();
  };

  for (int tb = 0; tb < T_; tb += 2) {
    step(tb,     0, xwA);
    step(tb + 1, 1, xwB);
  }
}

// ---------------------------------------------------------------------------
// Emissions via MFMA (unchanged).
// ---------------------------------------------------------------------------
__global__ __launch_bounds__(256, 1)
void emis_kernel(const _Float16* __restrict__ hcat,
                 const float* __restrict__ Wp, const float* __restrict__ bp,
                 float* __restrict__ em)
{
  const int tid  = threadIdx.x;
  const int w    = tid >> 6;
  const int lane = tid & 63;
  const int lm   = lane & 15;
  const int quad = lane >> 4;

  f16x8 Bf[3][8];
  float bias[3];
  #pragma unroll
  for (int nt = 0; nt < 3; ++nt) {
    const int n = nt * 16 + lm;
    const bool valid = n < K_;
    bias[nt] = valid ? bp[n] : 0.0f;
    #pragma unroll
    for (int kt = 0; kt < 8; ++kt) {
      const int kb = kt * 32 + quad * 8;
      #pragma unroll
      for (int j = 0; j < 8; ++j)
        Bf[nt][kt][j] = valid ? (_Float16)Wp[(size_t)n * 256 + kb + j] : (_Float16)0.0f;
    }
  }

  #pragma unroll
  for (int q = 0; q < 4; ++q) {
    const int mt  = blockIdx.x * 16 + w * 4 + q;
    const int bt0 = mt * 16;

    f16x8 Af[8];
    const _Float16* ab = hcat + ((size_t)bt0 + lm) * 256;
    #pragma unroll
    for (int kt = 0; kt < 8; ++kt)
      Af[kt] = *(const f16x8*)(ab + kt * 32 + quad * 8);

    f32x4 acc[3];
    #pragma unroll
    for (int nt = 0; nt < 3; ++nt) acc[nt] = (f32x4){0.f, 0.f, 0.f, 0.f};
    #pragma unroll
    for (int kt = 0; kt < 8; ++kt)
      #pragma unroll
      for (int nt = 0; nt < 3; ++nt)
        acc[nt] = __builtin_amdgcn_mfma_f32_16x16x32_f16(Af[kt], Bf[nt][kt], acc[nt], 0, 0, 0);

    #pragma unroll
    for (int nt = 0; nt < 3; ++nt) {
      const int n = nt * 16 + lm;
      if (n < K_) {
        #pragma unroll
        for (int rg = 0; rg < 4; ++rg) {
          const int row = bt0 + quad * 4 + rg;
          em[(size_t)row * K_ + n] = acc[nt][rg] + bias[nt];
        }
      }
    }
  }
}

// ---------------------------------------------------------------------------
// Fused CRF den+num. Grid 64, 256 threads. em staged in LDS (2 phases).
// Den (wave 0): readlane broadcast in TWO PHASES — all 39 v_readlane into
// SGPRs first, sched_barrier, then the 39 FMAs. The R12 interleaved form
// paid a VALU-writes-SGPR -> VALU-reads-SGPR hazard (~13 cyc) on every pair
// (~500 cyc/step); batching puts >=39 instructions between each readlane
// and its consumer, eliminating the wait states. (R13's LDS pbuf broadcast
// was worse: serial ds round-trip ~250 cyc/step.)
// Waves 1-3: numerator (global reads, phase 0).
// ---------------------------------------------------------------------------
__global__ __launch_bounds__(256)
void crf_dn_kernel(const float* __restrict__ em,
                   const int* __restrict__ labels, const int* __restrict__ lengths,
                   const float* __restrict__ start_t, const float* __restrict__ end_t,
                   const float* __restrict__ trans,
                   float* __restrict__ dn)
{
  const int b    = blockIdx.x;
  const int tid  = threadIdx.x;
  const int wv   = tid >> 6;
  const int lane = tid & 63;
  const int len  = lengths[b];
  const float* emb = em + (size_t)b * T_ * K_;

  __shared__ alignas(16) float ems[408 * K_];   // 63.6 KB
  __shared__ float s_red[4];

  float et[K_];
  float v = 0.f, off_acc = 0.f, num_acc = 0.f;

  if (wv == 0) {
    #pragma unroll
    for (int j = 0; j < K_; ++j)
      et[j] = (lane < K_) ? __expf(trans[j * K_ + lane]) : 0.0f;
    float a0 = (lane < K_) ? (start_t[lane] + emb[lane]) : -1e30f;
    float m = a0;
    #pragma unroll
    for (int off = 32; off > 0; off >>= 1) m = fmaxf(m, __shfl_xor(m, off));
    v = __expf(a0 - m);               // lanes >= 39 -> 0
    off_acc = m;
  }

  for (int p = 0; p < 2; ++p) {
    const int rbase = p * 408;                   // staged row range start
    const int rcnt  = p ? 392 : 408;             // phase1: rows 408..799
    {
      const float4* src = (const float4*)(emb + (size_t)rbase * K_);
      for (int i = tid; i < rcnt * K_ / 4; i += 256)
        ((float4*)ems)[i] = src[i];
    }
    __syncthreads();

    if (wv == 0) {
      const int ts = p ? 408 : 1;
      const int te = p ? T_ : 408;
      float emn = (lane < K_) ? ems[(ts - rbase) * K_ + lane] : 0.f;
      for (int t = ts; t < te; ++t) {
        const float emc = emn;
        const int tn = (t + 1 < te) ? (t + 1) : (te - 1);
        emn = (lane < K_) ? ems[(tn - rbase) * K_ + lane] : 0.f;   // prefetch

        const float pv = v;
        // phase 1: batch ALL readlanes into SGPRs
        float sv[K_];
        #pragma unroll
        for (int j = 0; j < K_; ++j) sv[j] = laneb_(pv, j);
        __builtin_amdgcn_sched_barrier(0);
        // phase 2: hazard-free FMA tree
        float s0 = 0.f, s1 = 0.f, s2 = 0.f, s3 = 0.f;
        #pragma unroll
        for (int j = 0; j < 36; j += 4) {
          s0 = fmaf(sv[j],     et[j],     s0);
          s1 = fmaf(sv[j + 1], et[j + 1], s1);
          s2 = fmaf(sv[j + 2], et[j + 2], s2);
          s3 = fmaf(sv[j + 3], et[j + 3], s3);
        }
        s0 = fmaf(sv[36], et[36], s0);
        s1 = fmaf(sv[37], et[37], s1);
        s2 = fmaf(sv[38], et[38], s2);
        const float nv = ((s0 + s1) + (s2 + s3)) * __expf(emc);
        v = (t < len) ? nv : v;         // freeze past len (matches jnp.where)
        if ((t & 3) == 0) {             // algebra-neutral renorm, VALU only
          const float sc = laneb_(v, 0);  // strictly positive
          v *= __builtin_amdgcn_rcpf(sc);
          off_acc += __logf(sc);
        }
      }
    } else if (p == 0) {
      // numerator over full range (global reads, latency-tolerant)
      const int idx = tid - 64;       // 0..191
      for (int t = 1 + idx; t < len; t += 192) {
        const int lp = labels[b * T_ + t - 1];
        const int lc = labels[b * T_ + t];
        num_acc += trans[lp * K_ + lc] + emb[(size_t)t * K_ + lc];
      }
      if (tid == 64) {                // edge terms on one lane
        const int l0 = labels[b * T_];
        const int ll = labels[b * T_ + len - 1];
        num_acc += start_t[l0] + emb[l0] + end_t[ll];
      }
    }
    __syncthreads();
  }

  if (wv == 0) {
    float w = (lane < K_) ? v * __expf(end_t[lane]) : 0.0f;
    #pragma unroll
    for (int off = 32; off > 0; off >>= 1) w += __shfl_xor(w, off);
    if (lane == 0) s_red[0] = off_acc + __logf(w);
  } else {
    float acc = num_acc;
    #pragma unroll
    for (int off = 32; off > 0; off >>= 1) acc += __shfl_xor(acc, off);
    if (lane == 0) s_red[wv] = acc;
  }
  __syncthreads();
  if (tid == 0) dn[b] = s_red[0] - (s_red[1] + s_red[2] + s_red[3]);
}

// out = mean(dn) over the 64 batch elements (one wave).
__global__ void finalize_kernel(const float* __restrict__ dn, float* __restrict__ out)
{
  const int tid = threadIdx.x;   // 64
  float v = dn[tid];
  #pragma unroll
  for (int off = 32; off > 0; off >>= 1) v += __shfl_down(v, off);
  if (tid == 0) out[0] = v * (1.0f / 64.0f);
}

extern "C" void kernel_launch(void* const* d_in, const int* in_sizes, int n_in,
                              void* d_out, int out_size, void* d_ws, size_t ws_size,
                              hipStream_t stream)
{
  (void)in_sizes; (void)n_in; (void)out_size;
  const float* features = (const float*)d_in[0];
  const int*   lengths  = (const int*)d_in[1];
  const int*   labels   = (const int*)d_in[2];
  const float* Wih_f = (const float*)d_in[3];
  const float* Whh_f = (const float*)d_in[4];
  const float* bih_f = (const float*)d_in[5];
  const float* bhh_f = (const float*)d_in[6];
  const float* Wih_b = (const float*)d_in[7];
  const float* Whh_b = (const float*)d_in[8];
  const float* bih_b = (const float*)d_in[9];
  const float* bhh_b = (const float*)d_in[10];
  const float* Wp      = (const float*)d_in[11];
  const float* bp      = (const float*)d_in[12];
  const float* start_t = (const float*)d_in[13];
  const float* end_t   = (const float*)d_in[14];
  const float* trans   = (const float*)d_in[15];
  float* out = (float*)d_out;

  // ws layout (bytes): hcat f16 [0, 26214400) ; em f32 [26214400, +7987200) ;
  // dn 256 B ; xw f16 [34202112, +104857600) if ws is big enough.
  char* wsc = (char*)d_ws;
  _Float16* hcatH = (_Float16*)wsc;
  float*    em    = (float*)(wsc + 26214400);
  float*    dn    = (float*)(wsc + 26214400 + 7987200);
  _Float16* xwH   = (_Float16*)(wsc + 34202112);
  const bool big  = ws_size >= (size_t)34202112 + 104857600;

  if (big) {
    hipLaunchKernelGGL(xw_kernel, dim3(200), dim3(256), 0, stream,
                       features, Wih_f, Wih_b, xwH);
    hipLaunchKernelGGL((lstm_kernel<1>), dim3(2 * B_), dim3(256), 0, stream,
                       features, Wih_f, Whh_f, bih_f, bhh_f,
                       Wih_b, Whh_b, bih_b, bhh_b, xwH, hcatH);
  } else {
    hipLaunchKernelGGL((lstm_kernel<0>), dim3(2 * B_), dim3(256), 0, stream,
                       features, Wih_f, Whh_f, bih_f, bhh_f,
                       Wih_b, Whh_b, bih_b, bhh_b, xwH, hcatH);
  }
  hipLaunchKernelGGL(emis_kernel, dim3(BT_ / 256), dim3(256), 0, stream,
                     hcatH, Wp, bp, em);
  hipLaunchKernelGGL(crf_dn_kernel, dim3(B_), dim3(256), 0, stream,
                     em, labels, lengths, start_t, end_t, trans, dn);
  hipLaunchKernelGGL(finalize_kernel, dim3(1), dim3(64), 0, stream,
                     dn, out);
}